// Round 7
// baseline (174.172 us; speedup 1.0000x reference)
//
#include <hip/hip_runtime.h>
#include <hip/hip_bf16.h>

#define D_ 128
#define E_ 100
#define K_ 4
#define C_ 400
#define ECH 10        // chunks per element in k_assign -> 1000 blocks
#define SB 64         // escatter blocks

// ws layout (f32 slots):
//   [0, 51200)        sums f32[C][D]      (atomic, zeroed)
//   [51200, 51600)    countsF f32[C]      (atomic, zeroed)
//   [51600]           loss f32            (atomic, zeroed)
//   [51601, 51701)    ehist u32[E]        (atomic, zeroed)
//   [51701, 51801)    eoff u32[E]
//   [51801, 51901)    ecur u32[E]
//   [51901, +N)       sorted int[N]       (atom ids grouped by element)
#define OFF_COUNTS 51200
#define OFF_LOSS   51600
#define OFF_EHIST  51601
#define OFF_EOFF   51701
#define OFF_ECUR   51801
#define OFF_SORTED 51901

__global__ __launch_bounds__(256) void k_ehist(
    const int* __restrict__ ei, unsigned* __restrict__ ehist, int N) {
  __shared__ unsigned lh[E_];
  for (int i = threadIdx.x; i < E_; i += 256) lh[i] = 0u;
  __syncthreads();
  int stride = gridDim.x * 256;
  for (int a = blockIdx.x * 256 + threadIdx.x; a < N; a += stride)
    atomicAdd(&lh[ei[a]], 1u);
  __syncthreads();
  for (int i = threadIdx.x; i < E_; i += 256)
    if (lh[i]) atomicAdd(&ehist[i], lh[i]);
}

__global__ __launch_bounds__(128) void k_eprefix(
    const unsigned* __restrict__ ehist, unsigned* __restrict__ eoff,
    unsigned* __restrict__ ecur) {
  __shared__ unsigned s[128];
  int t = threadIdx.x;
  unsigned v = (t < E_) ? ehist[t] : 0u;
  s[t] = v;
  __syncthreads();
  for (int o = 1; o < 128; o <<= 1) {
    unsigned x = (t >= o) ? s[t - o] : 0u;
    __syncthreads();
    s[t] += x;
    __syncthreads();
  }
  if (t < E_) { unsigned ex = s[t] - v; eoff[t] = ex; ecur[t] = ex; }
}

__global__ __launch_bounds__(256) void k_escatter(
    const int* __restrict__ ei, unsigned* __restrict__ ecur,
    int* __restrict__ sorted, int N) {
  __shared__ unsigned lh[E_], lbase[E_], lcur[E_];
  const int chunk = (N + SB - 1) / SB;
  const int a0 = blockIdx.x * chunk;
  const int a1 = min(a0 + chunk, N);
  for (int i = threadIdx.x; i < E_; i += 256) { lh[i] = 0u; lcur[i] = 0u; }
  __syncthreads();
  for (int a = a0 + threadIdx.x; a < a1; a += 256) atomicAdd(&lh[ei[a]], 1u);
  __syncthreads();
  for (int i = threadIdx.x; i < E_; i += 256)
    lbase[i] = lh[i] ? atomicAdd(&ecur[i], lh[i]) : 0u;
  __syncthreads();
  for (int a = a0 + threadIdx.x; a < a1; a += 256) {
    int e = ei[a];
    unsigned r = atomicAdd(&lcur[e], 1u);
    sorted[lbase[e] + r] = a;
  }
}

// DPP xor-reduce helper (template forces compile-time immediates).
template <int CTRL>
__device__ __forceinline__ float dpp_add(float x) {
  int y = __builtin_amdgcn_update_dpp(0, __builtin_bit_cast(int, x),
                                      CTRL, 0xF, 0xF, true);
  return x + __builtin_bit_cast(float, y);
}

// Fused assign + segment-sum. Block = (element, chunk); 4 waves; each wave
// processes 4 atoms/iteration: 16 lanes per atom, 8 floats (2x float4) per
// lane. Codebook rows in registers; 16-lane reduce = 4 DPP steps (no DS).
__global__ __launch_bounds__(256) void k_assign(
    const float* __restrict__ h, const float* __restrict__ cb,
    const int* __restrict__ sorted, const unsigned* __restrict__ eoff,
    const unsigned* __restrict__ ehist, float* __restrict__ hq,
    float* __restrict__ at, float* __restrict__ sums,
    float* __restrict__ countsF, float* __restrict__ lossp) {
  const int e = blockIdx.x / ECH;
  const int kk = blockIdx.x % ECH;
  const int cnt = (int)ehist[e];
  const int base = (int)eoff[e];
  const int sz = (cnt + ECH - 1) / ECH;
  const int lo = kk * sz;
  const int hi = min(lo + sz, cnt);
  const int w = threadIdx.x >> 6;
  const int lane = threadIdx.x & 63;
  const int g = lane >> 4;   // group (atom slot) within wave
  const int t = lane & 15;   // lane within group: dims [t*8, t*8+8)
  const int e4 = e * K_;

  const float4* cb4 = (const float4*)cb;
  const float4* h4 = (const float4*)h;
  float4* hq4 = (float4*)hq;

  float4 cA[4], cB[4];
#pragma unroll
  for (int j = 0; j < 4; ++j) {
    cA[j] = cb4[(size_t)(e4 + j) * 32 + t * 2];
    cB[j] = cb4[(size_t)(e4 + j) * 32 + t * 2 + 1];
  }

  float4 sAcc[4] = {}, sBcc[4] = {};
  float cf[4] = {};
  float lossl = 0.f;

  const int rem = hi - lo - w * 4;          // work remaining for this wave's lanes
  const int nit = (rem > 0) ? ((rem + 15) >> 4) : 0;   // wave-uniform

  int idx = lo + w * 4 + g;
  bool act = idx < hi;
  int aid = 0; float4 hA = {}, hB = {};
  if (act) {
    aid = sorted[base + idx];
    hA = h4[(size_t)aid * 32 + t * 2];
    hB = h4[(size_t)aid * 32 + t * 2 + 1];
  }

  for (int it = 0; it < nit; ++it) {
    // prefetch next 4 atoms for this wave
    int idn = idx + 16;
    bool actn = idn < hi;
    int aidn = 0; float4 hAn = {}, hBn = {};
    if (actn) {
      aidn = sorted[base + idn];
      hAn = h4[(size_t)aidn * 32 + t * 2];
      hBn = h4[(size_t)aidn * 32 + t * 2 + 1];
    }

    float p[4];
#pragma unroll
    for (int j = 0; j < 4; ++j) {
      float d0 = hA.x - cA[j].x, d1 = hA.y - cA[j].y;
      float d2 = hA.z - cA[j].z, d3 = hA.w - cA[j].w;
      float d4 = hB.x - cB[j].x, d5 = hB.y - cB[j].y;
      float d6 = hB.z - cB[j].z, d7 = hB.w - cB[j].w;
      p[j] = ((d0*d0 + d1*d1) + (d2*d2 + d3*d3)) +
             ((d4*d4 + d5*d5) + (d6*d6 + d7*d7));
    }
    // reduce across the 16-lane group: pure DPP butterfly (no DS ops)
#pragma unroll
    for (int j = 0; j < 4; ++j) {
      p[j] = dpp_add<0xB1>(p[j]);    // quad_perm xor1
      p[j] = dpp_add<0x4E>(p[j]);    // quad_perm xor2
      p[j] = dpp_add<0x141>(p[j]);   // row_half_mirror (crosses quads)
      p[j] = dpp_add<0x140>(p[j]);   // row_mirror (crosses 8-groups)
    }
    int best = 0; float bp = p[0];
    if (p[1] < bp) { bp = p[1]; best = 1; }
    if (p[2] < bp) { bp = p[2]; best = 2; }
    if (p[3] < bp) { bp = p[3]; best = 3; }

    if (act) {
      float4 qA = cA[0], qB = cB[0];
      if (best == 1) { qA = cA[1]; qB = cB[1]; }
      if (best == 2) { qA = cA[2]; qB = cB[2]; }
      if (best == 3) { qA = cA[3]; qB = cB[3]; }
      hq4[(size_t)aid * 32 + t * 2]     = qA;
      hq4[(size_t)aid * 32 + t * 2 + 1] = qB;
      if (t == 0) { at[aid] = (float)(e4 + best); lossl += bp; }
#pragma unroll
      for (int j = 0; j < 4; ++j) {
        float m = (best == j) ? 1.f : 0.f;
        sAcc[j].x = fmaf(m, hA.x, sAcc[j].x);
        sAcc[j].y = fmaf(m, hA.y, sAcc[j].y);
        sAcc[j].z = fmaf(m, hA.z, sAcc[j].z);
        sAcc[j].w = fmaf(m, hA.w, sAcc[j].w);
        sBcc[j].x = fmaf(m, hB.x, sBcc[j].x);
        sBcc[j].y = fmaf(m, hB.y, sBcc[j].y);
        sBcc[j].z = fmaf(m, hB.z, sBcc[j].z);
        sBcc[j].w = fmaf(m, hB.w, sBcc[j].w);
        cf[j] += m;
      }
    }
    idx = idn; act = actn; aid = aidn; hA = hAn; hB = hBn;
  }

  // epilogue: reduce across the 4 groups (lanes l, l^16, l^32, l^48), flush.
#pragma unroll
  for (int j = 0; j < 4; ++j) {
    float v[8] = { sAcc[j].x, sAcc[j].y, sAcc[j].z, sAcc[j].w,
                   sBcc[j].x, sBcc[j].y, sBcc[j].z, sBcc[j].w };
#pragma unroll
    for (int d = 0; d < 8; ++d) {
      float x = v[d];
      x += __shfl_xor(x, 16, 64);
      x += __shfl_xor(x, 32, 64);
      if (lane < 16) atomicAdd(&sums[(size_t)(e4 + j) * D_ + t * 8 + d], x);
    }
    float cv = cf[j];
    cv += __shfl_xor(cv, 16, 64);
    cv += __shfl_xor(cv, 32, 64);
    if (lane == 0 && cv != 0.f) atomicAdd(&countsF[e4 + j], cv);
  }
  float lv = lossl;
  lv += __shfl_xor(lv, 16, 64);
  lv += __shfl_xor(lv, 32, 64);
  if (lane == 0 && lv != 0.f) atomicAdd(lossp, lv);
}

// EMA finalize + loss scalar (f32 counts).
__global__ __launch_bounds__(256) void k_final(
    const float* __restrict__ cb, const float* __restrict__ ecnt,
    const float* __restrict__ esum, const float* __restrict__ ws,
    float* __restrict__ out, int N) {
  const float* sums = ws;
  const float* countsF = ws + OFF_COUNTS;
  int idx = blockIdx.x * 256 + threadIdx.x;
  const size_t base = (size_t)N * D_ + N + 1;
  if (idx < C_ * D_) {
    int c = idx >> 7;
    int e4 = (c >> 2) << 2;
    bool present = (countsF[e4] + countsF[e4 + 1] + countsF[e4 + 2] + countsF[e4 + 3]) > 0.f;
    float es = esum[idx];
    float s  = sums[idx];
    float ns = present ? 0.99f * es + 0.01f * s : es;
    float ec = ecnt[c];
    float nc = present ? 0.99f * ec + 0.01f * countsF[c] : ec;
    float ncbv = present ? ns / fmaxf(nc, 1e-5f) : cb[idx];
    out[base + idx] = ncbv;
    if ((idx & 127) == 0) out[base + C_ * D_ + c] = nc;
    out[base + C_ * D_ + C_ + idx] = ns;
  }
  if (idx == 0) {
    float loss = ws[OFF_LOSS];
    out[(size_t)N * D_ + N] = 0.25f * loss / ((float)N * (float)D_);
  }
}

extern "C" void kernel_launch(void* const* d_in, const int* in_sizes, int n_in,
                              void* d_out, int out_size, void* d_ws, size_t ws_size,
                              hipStream_t stream) {
  // Identify inputs by size (robust to input-order changes).
  const float* h = nullptr; const int* ei = nullptr;
  const float* cb = nullptr; const float* ecnt = nullptr; const float* esum = nullptr;
  long hsz = -1; int hidx = -1;
  for (int i = 0; i < n_in; ++i)
    if ((long)in_sizes[i] > hsz) { hsz = in_sizes[i]; hidx = i; }
  h = (const float*)d_in[hidx];
  const int N = (int)(hsz / D_);
  for (int i = 0; i < n_in; ++i) {
    if (i == hidx) continue;
    const int s = in_sizes[i];
    if (s == N) ei = (const int*)d_in[i];
    else if (s == C_) ecnt = (const float*)d_in[i];
    else if (s == C_ * D_) { if (!cb) cb = (const float*)d_in[i]; else esum = (const float*)d_in[i]; }
  }

  float* out = (float*)d_out;
  float* hq  = out;
  float* at  = out + (size_t)N * D_;

  float* ws = (float*)d_ws;
  float*    sums    = ws;
  float*    countsF = ws + OFF_COUNTS;
  float*    lossp   = ws + OFF_LOSS;
  unsigned* ehist   = (unsigned*)(ws + OFF_EHIST);
  unsigned* eoff    = (unsigned*)(ws + OFF_EOFF);
  unsigned* ecur    = (unsigned*)(ws + OFF_ECUR);
  int*      sorted  = (int*)(ws + OFF_SORTED);

  // zero sums/counts/loss/ehist in one range
  hipMemsetAsync(d_ws, 0, (size_t)OFF_EOFF * 4, stream);

  k_ehist<<<64, 256, 0, stream>>>(ei, ehist, N);
  k_eprefix<<<1, 128, 0, stream>>>(ehist, eoff, ecur);
  k_escatter<<<SB, 256, 0, stream>>>(ei, ecur, sorted, N);
  k_assign<<<E_ * ECH, 256, 0, stream>>>(h, cb, sorted, eoff, ehist,
                                         hq, at, sums, countsF, lossp);
  k_final<<<(C_ * D_ + 255) / 256, 256, 0, stream>>>(cb, ecnt, esum, ws, out, N);
}